// Round 3
// baseline (935.804 us; speedup 1.0000x reference)
//
#include <hip/hip_runtime.h>
#include <stdint.h>

typedef short short8 __attribute__((ext_vector_type(8)));
typedef float floatx4 __attribute__((ext_vector_type(4)));

#define BIAS 8.0f

__device__ __forceinline__ unsigned short f2bf(float f) {
    unsigned int u = __float_as_uint(f);
    unsigned int r = (u + 0x7FFFu + ((u >> 16) & 1u)) >> 16;   // RNE
    return (unsigned short)r;
}

// ---------------- kernel 0: W -> bf16(-w) in MFMA-B-fragment order, + zero loss slot
// short8 slot s: T=s>>7 (16-code tile), h=(s>>6)&1 (k half), l=s&63 (lane)
// value[j] = -W[T*16 + (l&15)][h*32 + (l>>4)*8 + j]
__global__ void vq_prep(const float* __restrict__ W, unsigned short* __restrict__ Wsw,
                        float* __restrict__ out0) {
    const int s = blockIdx.x * 256 + threadIdx.x;      // 32768 slots
    const int T = s >> 7;
    const int h = (s >> 6) & 1;
    const int l = s & 63;
    const int code = T * 16 + (l & 15);
    const float* src = W + code * 64 + h * 32 + (l >> 4) * 8;
    const floatx4* sp = (const floatx4*)src;
    floatx4 f0 = sp[0], f1 = sp[1];
    short8 fr;
    fr[0] = (short)f2bf(-f0[0]); fr[1] = (short)f2bf(-f0[1]);
    fr[2] = (short)f2bf(-f0[2]); fr[3] = (short)f2bf(-f0[3]);
    fr[4] = (short)f2bf(-f1[0]); fr[5] = (short)f2bf(-f1[1]);
    fr[6] = (short)f2bf(-f1[2]); fr[7] = (short)f2bf(-f1[3]);
    ((short8*)Wsw)[s] = fr;
    if (s == 0) *out0 = 0.0f;
}

// ---- one 16-code tile (k=64 via 2 chained MFMAs) against all 4 row-tiles
__device__ __forceinline__ void dist_tile(const short8 (&af)[4][2],
                                          short8 c0, short8 c1, unsigned int kk,
                                          unsigned int (&minpk)[4][4]) {
    const floatx4 bias4 = {BIAS, BIAS, BIAS, BIAS};
    #pragma unroll
    for (int mt = 0; mt < 4; ++mt) {
        floatx4 acc = __builtin_amdgcn_mfma_f32_16x16x32_bf16(af[mt][0], c0, bias4, 0, 0, 0);
        acc = __builtin_amdgcn_mfma_f32_16x16x32_bf16(af[mt][1], c1, acc, 0, 0, 0);
        #pragma unroll
        for (int r = 0; r < 4; ++r) {
            unsigned int p = __float_as_uint(acc[r]) | kk;   // monotone pack
            minpk[mt][r] = p < minpk[mt][r] ? p : minpk[mt][r];
        }
    }
}

// ---- inline-asm B-stream into NAMED registers (no arrays, no pointers -> no
// scratch demotion; R2's s[3][4] array was address-taken and spilled, rule #20).
// Program-order-pinned loads + hand-counted vmcnt; sched_barrier(0) after the
// waitcnt stops MFMAs hoisting above it (rule 18).
#define ISSUE4(d0, d1, d2, d3, base) do {                                             \
    const char* _a = (base);                                                          \
    asm volatile("global_load_dwordx4 %0, %1, off"             : "=v"(d0) : "v"(_a)); \
    asm volatile("global_load_dwordx4 %0, %1, off offset:1024" : "=v"(d1) : "v"(_a)); \
    asm volatile("global_load_dwordx4 %0, %1, off offset:2048" : "=v"(d2) : "v"(_a)); \
    asm volatile("global_load_dwordx4 %0, %1, off offset:3072" : "=v"(d3) : "v"(_a)); \
} while (0)

#define VWAIT8 do { asm volatile("s_waitcnt vmcnt(8)" ::: "memory"); \
                    __builtin_amdgcn_sched_barrier(0); } while (0)
#define VWAIT0 do { asm volatile("s_waitcnt vmcnt(0)" ::: "memory"); \
                    __builtin_amdgcn_sched_barrier(0); } while (0)

// one pipeline step: consume slot (d0..d3) for group g, refill it for group g+3
// (tail groups issue a dummy reload of group 0 to keep the vmcnt cadence uniform;
// those registers are dead afterwards and drained by VWAIT0)
#define GROUP(d0, d1, d2, d3, g) do {                                          \
    VWAIT8;                                                                    \
    dist_tile(afrag, d0, d1, kidx0 + (unsigned)((g) * 32), minpk);             \
    dist_tile(afrag, d2, d3, kidx0 + (unsigned)((g) * 32 + 16), minpk);        \
    ISSUE4(d0, d1, d2, d3, wbase + (((g) + 3 < 32) ? ((g) + 3) : 0) * 4096);   \
} while (0)

#define GROUP3(gg)                       \
    GROUP(sA0, sA1, sA2, sA3, (gg));     \
    GROUP(sB0, sB1, sB2, sB3, (gg) + 1); \
    GROUP(sC0, sC1, sC2, sC3, (gg) + 2)

// ---------------- kernel 1: block = 64 rows x 4 waves (one codegroup each)
// B-stream pipelined in 3 named register slots x 4 loads (6KB/wave in flight).
// Latency slack = 2 groups of 16 MFMAs (~2500 CU cyc at 16-wave contention)
// >> L2 latency (~300 cyc).
__launch_bounds__(256)
__attribute__((amdgpu_waves_per_eu(4, 4)))
__global__ void vq_main(const float* __restrict__ z, const float* __restrict__ W,
                        const unsigned short* __restrict__ Wsw, float* __restrict__ out) {
    __shared__ unsigned int pk_lds[256];   // [wave][local row 0..63]
    __shared__ float ls[4];

    const int tid  = threadIdx.x;
    const int lane = tid & 63;
    const int cg   = tid >> 6;      // wave = code group (1024 codes each)
    const int l15  = lane & 15;
    const int lq   = lane >> 4;
    const int rowbase = blockIdx.x * 64;

    // ---- A fragments: the block's 64 rows x 64 k as bf16 (32 VGPR)
    short8 afrag[4][2];
    #pragma unroll
    for (int mt = 0; mt < 4; ++mt) {
        const float* zp = z + (rowbase + mt * 16 + l15) * 64 + lq * 8;
        #pragma unroll
        for (int h = 0; h < 2; ++h) {
            const floatx4* p = (const floatx4*)(zp + h * 32);
            floatx4 f0 = p[0], f1 = p[1];
            short8 fr;
            fr[0] = (short)f2bf(f0[0]); fr[1] = (short)f2bf(f0[1]);
            fr[2] = (short)f2bf(f0[2]); fr[3] = (short)f2bf(f0[3]);
            fr[4] = (short)f2bf(f1[0]); fr[5] = (short)f2bf(f1[1]);
            fr[6] = (short)f2bf(f1[2]); fr[7] = (short)f2bf(f1[3]);
            afrag[mt][h] = fr;
        }
    }

    unsigned int minpk[4][4];
    #pragma unroll
    for (int mt = 0; mt < 4; ++mt)
        #pragma unroll
        for (int r = 0; r < 4; ++r) minpk[mt][r] = 0xFFFFFFFFu;

    // ---- B-stream pipeline: 32 groups of 32 codes (4 x 16B loads each)
    const char* wbase = (const char*)Wsw + cg * 131072 + lane * 16;
    short8 sA0, sA1, sA2, sA3;   // slot A (groups 0,3,6,...)
    short8 sB0, sB1, sB2, sB3;   // slot B (groups 1,4,7,...)
    short8 sC0, sC1, sC2, sC3;   // slot C (groups 2,5,8,...)
    ISSUE4(sA0, sA1, sA2, sA3, wbase);
    ISSUE4(sB0, sB1, sB2, sB3, wbase + 4096);
    ISSUE4(sC0, sC1, sC2, sC3, wbase + 8192);

    const unsigned int kidx0 = (unsigned int)(cg * 1024 + l15);
    GROUP3(0);  GROUP3(3);  GROUP3(9 - 3);  GROUP3(9);  GROUP3(12);
    GROUP3(15); GROUP3(18); GROUP3(21);     GROUP3(24); GROUP3(27);
    GROUP(sA0, sA1, sA2, sA3, 30);
    GROUP(sB0, sB1, sB2, sB3, 31);
    VWAIT0;   // drain dummy tail loads before their registers are reused

    // ---- reduce across the 16 code-columns (lane bits 0..3), publish per-wave mins
    #pragma unroll
    for (int mt = 0; mt < 4; ++mt)
        #pragma unroll
        for (int r = 0; r < 4; ++r) {
            unsigned int v = minpk[mt][r];
            #pragma unroll
            for (int m = 1; m < 16; m <<= 1) {
                unsigned int o = (unsigned int)__shfl_xor((int)v, m, 64);
                v = o < v ? o : v;
            }
            if (l15 == 0) pk_lds[cg * 64 + mt * 16 + lq * 4 + r] = v;
        }
    __syncthreads();

    // ---- epilogue: wave w owns rows w*16 .. w*16+15 (of the block's 64)
    const int rl  = cg * 16 + l15;        // 0..63
    unsigned int v0 = pk_lds[rl];
    unsigned int v1 = pk_lds[64 + rl];
    unsigned int v2 = pk_lds[128 + rl];
    unsigned int v3 = pk_lds[192 + rl];
    unsigned int vm = v0 < v1 ? v0 : v1;
    unsigned int vn = v2 < v3 ? v2 : v3;
    unsigned int idx = (vm < vn ? vm : vn) & 0xFFFu;

    const int row = rowbase + rl;
    float loss = 0.0f;
    #pragma unroll
    for (int h = 0; h < 2; ++h) {
        const floatx4* wp = (const floatx4*)(W + idx * 64 + h * 32 + lq * 8);
        const floatx4* zp = (const floatx4*)(z + row * 64 + h * 32 + lq * 8);
        floatx4* op = (floatx4*)(out + 1 + row * 64 + h * 32 + lq * 8);
        #pragma unroll
        for (int part = 0; part < 2; ++part) {
            floatx4 wv = wp[part];
            floatx4 zv = zp[part];
            op[part] = wv;
            #pragma unroll
            for (int j = 0; j < 4; ++j) {
                float d = zv[j] - wv[j];
                loss = fmaf(d, d, loss);
            }
        }
    }
    #pragma unroll
    for (int m = 1; m < 64; m <<= 1) loss += __shfl_xor(loss, m, 64);
    if (lane == 0) ls[cg] = loss;
    __syncthreads();
    if (tid == 0) {
        float t = (ls[0] + ls[1]) + (ls[2] + ls[3]);
        atomicAdd(out, t * (0.25f / 4194304.0f));
    }
}

extern "C" void kernel_launch(void* const* d_in, const int* in_sizes, int n_in,
                              void* d_out, int out_size, void* d_ws, size_t ws_size,
                              hipStream_t stream) {
    (void)in_sizes; (void)n_in; (void)out_size; (void)ws_size;
    const float* z = (const float*)d_in[0];
    const float* W = (const float*)d_in[1];
    unsigned short* Wsw = (unsigned short*)d_ws;     // 512 KB: bf16(-w), B-frag order
    float* out = (float*)d_out;

    vq_prep<<<128, 256, 0, stream>>>(W, Wsw, out);
    vq_main<<<1024, 256, 0, stream>>>(z, W, Wsw, out);
}

// Round 4
// 118.265 us; speedup vs baseline: 7.9128x; 7.9128x over previous
//
#include <hip/hip_runtime.h>
#include <stdint.h>

typedef short short8 __attribute__((ext_vector_type(8)));
typedef float floatx4 __attribute__((ext_vector_type(4)));
typedef __attribute__((address_space(3))) char lds_char;
typedef const __attribute__((address_space(1))) void* gbl_cptr;

#define BIAS 8.0f

__device__ __forceinline__ unsigned short f2bf(float f) {
    unsigned int u = __float_as_uint(f);
    unsigned int r = (u + 0x7FFFu + ((u >> 16) & 1u)) >> 16;   // RNE
    return (unsigned short)r;
}

// ---------------- kernel 0: W -> bf16(-w) in MFMA-B-fragment order, + zero loss slot
// short8 slot s: T=s>>7 (16-code tile), h=(s>>6)&1 (k half), l=s&63 (lane)
// value[j] = -W[T*16 + (l&15)][h*32 + (l>>4)*8 + j]
__global__ void vq_prep(const float* __restrict__ W, unsigned short* __restrict__ Wsw,
                        float* __restrict__ out0) {
    const int s = blockIdx.x * 256 + threadIdx.x;      // 32768 slots
    const int T = s >> 7;
    const int h = (s >> 6) & 1;
    const int l = s & 63;
    const int code = T * 16 + (l & 15);
    const float* src = W + code * 64 + h * 32 + (l >> 4) * 8;
    const floatx4* sp = (const floatx4*)src;
    floatx4 f0 = sp[0], f1 = sp[1];
    short8 fr;
    fr[0] = (short)f2bf(-f0[0]); fr[1] = (short)f2bf(-f0[1]);
    fr[2] = (short)f2bf(-f0[2]); fr[3] = (short)f2bf(-f0[3]);
    fr[4] = (short)f2bf(-f1[0]); fr[5] = (short)f2bf(-f1[1]);
    fr[6] = (short)f2bf(-f1[2]); fr[7] = (short)f2bf(-f1[3]);
    ((short8*)Wsw)[s] = fr;
    if (s == 0) *out0 = 0.0f;
}

// ---- one 16-code tile (k=64 via 2 chained MFMAs) against all 4 row-tiles
__device__ __forceinline__ void dist_tile(const short8 (&af)[4][2],
                                          short8 c0, short8 c1, unsigned int kk,
                                          unsigned int (&minpk)[4][4]) {
    const floatx4 bias4 = {BIAS, BIAS, BIAS, BIAS};
    #pragma unroll
    for (int mt = 0; mt < 4; ++mt) {
        floatx4 acc = __builtin_amdgcn_mfma_f32_16x16x32_bf16(af[mt][0], c0, bias4, 0, 0, 0);
        acc = __builtin_amdgcn_mfma_f32_16x16x32_bf16(af[mt][1], c1, acc, 0, 0, 0);
        #pragma unroll
        for (int r = 0; r < 4; ++r) {
            unsigned int p = __float_as_uint(acc[r]) | kk;   // monotone pack
            minpk[mt][r] = p < minpk[mt][r] ? p : minpk[mt][r];
        }
    }
}

// ---- DMA one 4KB group (4 chunks x 64 lanes x 16B) global -> private LDS buffer.
// global src is per-lane (wlane includes lane*16); LDS dest is wave-uniform base,
// HW writes lane i at base + i*16 (matching the read layout below).
#define STAGE(lbuf, gsrc) do {                                                              \
    const char* _g = (gsrc);                                                                \
    __builtin_amdgcn_global_load_lds((gbl_cptr)(_g),                                        \
        (__attribute__((address_space(3))) void*)((lbuf)),        16, 0, 0);                \
    __builtin_amdgcn_global_load_lds((gbl_cptr)(_g + 1024),                                 \
        (__attribute__((address_space(3))) void*)((lbuf) + 1024), 16, 0, 0);                \
    __builtin_amdgcn_global_load_lds((gbl_cptr)(_g + 2048),                                 \
        (__attribute__((address_space(3))) void*)((lbuf) + 2048), 16, 0, 0);                \
    __builtin_amdgcn_global_load_lds((gbl_cptr)(_g + 3072),                                 \
        (__attribute__((address_space(3))) void*)((lbuf) + 3072), 16, 0, 0);                \
} while (0)

// counted vmcnt: never drains the in-flight prefetch groups (T4). memory clobber
// walls keep STAGE DMAs and plain loads from crossing (exact counting).
#define VMWAIT(N) asm volatile("s_waitcnt vmcnt(" #N ")" ::: "memory")

// asm ds_read (compiler can't see LDS dep -> no auto vmcnt(0)); manual lgkmcnt(0)
// + sched_barrier(0) fences the MFMAs (rule 18).
#define BODY(off, kk0) do {                                                        \
    short8 c0, c1, c2, c3;                                                         \
    asm volatile("ds_read_b128 %0, %1"             : "=v"(c0) : "v"(off));         \
    asm volatile("ds_read_b128 %0, %1 offset:1024" : "=v"(c1) : "v"(off));         \
    asm volatile("ds_read_b128 %0, %1 offset:2048" : "=v"(c2) : "v"(off));         \
    asm volatile("ds_read_b128 %0, %1 offset:3072" : "=v"(c3) : "v"(off));         \
    asm volatile("s_waitcnt lgkmcnt(0)" ::: "memory");                             \
    __builtin_amdgcn_sched_barrier(0);                                             \
    dist_tile(afrag, c0, c1, (kk0), minpk);                                        \
    dist_tile(afrag, c2, c3, (kk0) + 16u, minpk);                                  \
} while (0)

// ---------------- kernel 1: block = 64 rows x 4 waves (one codegroup each).
// B-stream staged via global_load_lds into per-wave private triple-buffered LDS
// (no cross-wave sharing -> NO barriers in the K-loop). In-flight data lives in
// the memory system, not VGPRs -> no register-pressure spills (R2/R3 lesson).
__launch_bounds__(256)
__global__ void vq_main(const float* __restrict__ z, const float* __restrict__ W,
                        const unsigned short* __restrict__ Wsw, float* __restrict__ out) {
    __shared__ unsigned int pk_lds[256];   // [wave][local row 0..63]
    __shared__ float ls[4];
    __shared__ __attribute__((aligned(1024))) char bstage[4][3][4096];  // 48 KB

    const int tid  = threadIdx.x;
    const int lane = tid & 63;
    const int cg   = tid >> 6;      // wave = code group (1024 codes each)
    const int l15  = lane & 15;
    const int lq   = lane >> 4;
    const int rowbase = blockIdx.x * 64;

    // ---- A fragments: the block's 64 rows x 64 k as bf16 (32 VGPR)
    short8 afrag[4][2];
    #pragma unroll
    for (int mt = 0; mt < 4; ++mt) {
        const float* zp = z + (rowbase + mt * 16 + l15) * 64 + lq * 8;
        #pragma unroll
        for (int h = 0; h < 2; ++h) {
            const floatx4* p = (const floatx4*)(zp + h * 32);
            floatx4 f0 = p[0], f1 = p[1];
            short8 fr;
            fr[0] = (short)f2bf(f0[0]); fr[1] = (short)f2bf(f0[1]);
            fr[2] = (short)f2bf(f0[2]); fr[3] = (short)f2bf(f0[3]);
            fr[4] = (short)f2bf(f1[0]); fr[5] = (short)f2bf(f1[1]);
            fr[6] = (short)f2bf(f1[2]); fr[7] = (short)f2bf(f1[3]);
            afrag[mt][h] = fr;
        }
    }

    unsigned int minpk[4][4];
    #pragma unroll
    for (int mt = 0; mt < 4; ++mt)
        #pragma unroll
        for (int r = 0; r < 4; ++r) minpk[mt][r] = 0xFFFFFFFFu;

    // ---- LDS buffer bases (wave-uniform, readfirstlane -> clean M0 setup)
    unsigned baseA = (unsigned)(unsigned long long)(void*)&bstage[cg][0][0];
    baseA = __builtin_amdgcn_readfirstlane(baseA);
    lds_char* bufA = (lds_char*)(unsigned long long)baseA;
    lds_char* bufB = bufA + 4096;
    lds_char* bufC = bufA + 8192;
    const unsigned l16  = (unsigned)lane * 16u;
    const unsigned offA = baseA + l16;          // per-lane ds_read addresses
    const unsigned offB = offA + 4096u;
    const unsigned offC = offA + 8192u;

    const char* wlane = (const char*)Wsw + cg * 131072 + lane * 16;

    // drain A-fragment loads so vmcnt counts ONLY the DMA stream from here on
    asm volatile("s_waitcnt vmcnt(0)" ::: "memory");
    STAGE(bufA, wlane);            // group 0
    STAGE(bufB, wlane + 4096);     // group 1

    // ---- K loop: 32 groups of 32 codes; compute g while g+1, g+2 DMAs fly
    unsigned kb = (unsigned)(cg * 1024 + l15);
    const char* wnext = wlane + 8192;
    #pragma unroll 1
    for (int it = 0; it < 10; ++it) {
        STAGE(bufC, wnext);            // group 3it+2
        VMWAIT(8);                     // group 3it resident
        BODY(offA, kb);
        STAGE(bufA, wnext + 4096);     // group 3it+3
        VMWAIT(8);                     // group 3it+1 resident
        BODY(offB, kb + 32u);
        STAGE(bufB, wnext + 8192);     // group 3it+4
        VMWAIT(8);                     // group 3it+2 resident
        BODY(offC, kb + 64u);
        wnext += 12288; kb += 96u;
    }
    // tail: groups 30 (bufA), 31 (bufB) — in flight: 8 then 4 DMAs
    VMWAIT(4);
    BODY(offA, kb);
    VMWAIT(0);
    BODY(offB, kb + 32u);

    // ---- reduce across the 16 code-columns (lane bits 0..3), publish per-wave mins
    #pragma unroll
    for (int mt = 0; mt < 4; ++mt)
        #pragma unroll
        for (int r = 0; r < 4; ++r) {
            unsigned int v = minpk[mt][r];
            #pragma unroll
            for (int m = 1; m < 16; m <<= 1) {
                unsigned int o = (unsigned int)__shfl_xor((int)v, m, 64);
                v = o < v ? o : v;
            }
            if (l15 == 0) pk_lds[cg * 64 + mt * 16 + lq * 4 + r] = v;
        }
    __syncthreads();

    // ---- epilogue: wave w owns rows w*16 .. w*16+15 (of the block's 64)
    const int rl  = cg * 16 + l15;        // 0..63
    unsigned int v0 = pk_lds[rl];
    unsigned int v1 = pk_lds[64 + rl];
    unsigned int v2 = pk_lds[128 + rl];
    unsigned int v3 = pk_lds[192 + rl];
    unsigned int vm = v0 < v1 ? v0 : v1;
    unsigned int vn = v2 < v3 ? v2 : v3;
    unsigned int idx = (vm < vn ? vm : vn) & 0xFFFu;

    const int row = rowbase + rl;
    float loss = 0.0f;
    #pragma unroll
    for (int h = 0; h < 2; ++h) {
        const floatx4* wp = (const floatx4*)(W + idx * 64 + h * 32 + lq * 8);
        const floatx4* zp = (const floatx4*)(z + row * 64 + h * 32 + lq * 8);
        floatx4* op = (floatx4*)(out + 1 + row * 64 + h * 32 + lq * 8);
        #pragma unroll
        for (int part = 0; part < 2; ++part) {
            floatx4 wv = wp[part];
            floatx4 zv = zp[part];
            op[part] = wv;
            #pragma unroll
            for (int j = 0; j < 4; ++j) {
                float d = zv[j] - wv[j];
                loss = fmaf(d, d, loss);
            }
        }
    }
    #pragma unroll
    for (int m = 1; m < 64; m <<= 1) loss += __shfl_xor(loss, m, 64);
    if (lane == 0) ls[cg] = loss;
    __syncthreads();
    if (tid == 0) {
        float t = (ls[0] + ls[1]) + (ls[2] + ls[3]);
        atomicAdd(out, t * (0.25f / 4194304.0f));
    }
}

extern "C" void kernel_launch(void* const* d_in, const int* in_sizes, int n_in,
                              void* d_out, int out_size, void* d_ws, size_t ws_size,
                              hipStream_t stream) {
    (void)in_sizes; (void)n_in; (void)out_size; (void)ws_size;
    const float* z = (const float*)d_in[0];
    const float* W = (const float*)d_in[1];
    unsigned short* Wsw = (unsigned short*)d_ws;     // 512 KB: bf16(-w), B-frag order
    float* out = (float*)d_out;

    vq_prep<<<128, 256, 0, stream>>>(W, Wsw, out);
    vq_main<<<1024, 256, 0, stream>>>(z, W, Wsw, out);
}